// Round 12
// baseline (353.092 us; speedup 1.0000x reference)
//
#include <hip/hip_runtime.h>

#define HID 50
#define TSTEPS 512
#define NB 16   // batches per wave = MFMA N

typedef _Float16 h4 __attribute__((ext_vector_type(4)));
typedef __fp16   q4 __attribute__((ext_vector_type(4)));
typedef float    f4 __attribute__((ext_vector_type(4)));

// cvt_pkrtz/shufflevector produce __fp16 vectors; the MFMA builtin wants
// _Float16 vectors. Same bits -> memcpy bit-cast (compiles to nothing).
__device__ __forceinline__ h4 as_h4(q4 v) {
    h4 r; __builtin_memcpy(&r, &v, sizeof(r)); return r;
}

// MFMA-recurrence structure. Key fact (AMD matrix-core layouts, 16x16x16 f16):
//   A[i][k]: lane = 16*(k/4)+i, elem = k%4
//   B[k][n]: lane = 16*(k/4)+n, elem = k%4
//   D[i][n]: lane = 16*(i/4)+n, elem = i%4
// With M = hidden(out j), N = batch, K = hidden(in k): D's (row,elem) mapping
// EQUALS B's (k,elem) mapping, so tanh(D) IS the next step's B fragment in
// place: the matrix unit does the h all-to-all that cost 300-500 cyc/step in
// rounds 4-10 (LDS 651 cyc, readlane 834 cyc). No LDS, no barrier, no shuffle
// in the recurrence.
// Precision: 3-term f16 split GEMM (Ootomo-style): W*SC = Whi + Wlo/1024,
// h = hhi + hlo/1024 (lo stored x1024 so it stays f16-normal; Wlo magnitudes
// ~3e-5 would otherwise be denormal-flushed). z = Whi*hhi + (Whi*hlo' +
// Wlo'*hhi)/1024; dropped Wlo*hlo ~ 1e-8. Effectively fp32-exact.
__global__ __launch_bounds__(64) __attribute__((amdgpu_waves_per_eu(1, 1)))
void rnn_mfma(const float* __restrict__ x,      // [B, 512, 1]
              const float* __restrict__ W_ih,   // [50, 1]
              const float* __restrict__ W_hh,   // [50, 50]
              const float* __restrict__ b_ih,   // [50]
              const float* __restrict__ b_hh,   // [50]
              const float* __restrict__ W_fc,   // [1, 50]
              const float* __restrict__ b_fc,   // [1]
              float* __restrict__ out)          // [B, 1]
{
    const int l = threadIdx.x;
    const int c = l & 15;          // N col: batch within tile
    const int g = l >> 4;          // k-group / row-group
    const int bb = blockIdx.x * NB;
    const float SC = 2.8853900817779268f;   // 2*log2(e), folded into W/bias/x

    // ---- A fragments (W_hh, scaled by SC, hi/lo split), zero-padded 50->64
    h4 whi[4][4], wlo[4][4];
#pragma unroll
    for (int m = 0; m < 4; ++m) {
        const int j = m * 16 + c;
#pragma unroll
        for (int kt = 0; kt < 4; ++kt) {
#pragma unroll
            for (int e = 0; e < 4; ++e) {
                const int k = kt * 16 + 4 * g + e;
                const float v = (j < HID && k < HID) ? W_hh[j * HID + k] * SC : 0.0f;
                const _Float16 hi = (_Float16)v;
                whi[m][kt][e] = hi;
                wlo[m][kt][e] = (_Float16)((v - (float)hi) * 1024.0f);
            }
        }
    }
    // ---- per-lane C/D-layout constants: j = m*16 + 4g + e
    f4 wih_f[4], bias_f[4], wfc_f[4];
#pragma unroll
    for (int m = 0; m < 4; ++m) {
#pragma unroll
        for (int e = 0; e < 4; ++e) {
            const int j = m * 16 + 4 * g + e;
            wih_f[m][e]  = (j < HID) ? W_ih[j] * SC : 0.0f;
            bias_f[m][e] = (j < HID) ? (b_ih[j] + b_hh[j]) * SC : 0.0f;
            wfc_f[m][e]  = (j < HID) ? W_fc[j] : 0.0f;   // fc NOT scaled
        }
    }
    const float bfc = b_fc[0];

    h4 bhi[4] = {}, blo[4] = {};   // h state fragments; h0 = 0
    f4 hf[4];                      // current h (f32), for the fc epilogue
    const f4 kZ = {0.0f, 0.0f, 0.0f, 0.0f};
    const float INV = 1.0f / 1024.0f;

    // x: one float4 per 4 steps per lane (16B aligned; addr uniform across the
    // 4 g-groups -> broadcast). Prefetched one group ahead.
    const float4* xp = reinterpret_cast<const float4*>(x + (size_t)(bb + c) * TSTEPS);
    float4 xq = xp[0];

    for (int ch = 0; ch < TSTEPS / 4; ++ch) {
        const int nxt = (ch + 1 < TSTEPS / 4) ? ch + 1 : ch;   // clamp, no OOB
        const float4 xqn = xp[nxt];
        const float xa[4] = {xq.x, xq.y, xq.z, xq.w};
#pragma unroll
        for (int s = 0; s < 4; ++s) {
            const float xt = xa[s];
            f4 acc[4], accl[4];
            // C-init: exact-fp32 x-projection + bias (scaled by SC)
#pragma unroll
            for (int m = 0; m < 4; ++m)
#pragma unroll
                for (int e = 0; e < 4; ++e)
                    acc[m][e] = fmaf(xt, wih_f[m][e], bias_f[m][e]);
            // MFMA: hi term into acc; two lo cross-terms (x1024) into accl
#pragma unroll
            for (int m = 0; m < 4; ++m) {
#pragma unroll
                for (int kt = 0; kt < 4; ++kt)
                    acc[m] = __builtin_amdgcn_mfma_f32_16x16x16f16(
                        whi[m][kt], bhi[kt], acc[m], 0, 0, 0);
                accl[m] = __builtin_amdgcn_mfma_f32_16x16x16f16(
                    whi[m][0], blo[0], kZ, 0, 0, 0);
#pragma unroll
                for (int kt = 1; kt < 4; ++kt)
                    accl[m] = __builtin_amdgcn_mfma_f32_16x16x16f16(
                        whi[m][kt], blo[kt], accl[m], 0, 0, 0);
#pragma unroll
                for (int kt = 0; kt < 4; ++kt)
                    accl[m] = __builtin_amdgcn_mfma_f32_16x16x16f16(
                        wlo[m][kt], bhi[kt], accl[m], 0, 0, 0);
            }
            // combine + tanh + repack (D layout == B layout: in-lane only).
            // Padded rows (j>=50) have zero A-row/wih/bias -> acc=0 -> h=0,
            // so pad slots (k=50..63) regenerate as zero with no masking.
#pragma unroll
            for (int m = 0; m < 4; ++m) {
#pragma unroll
                for (int e = 0; e < 4; ++e) {
                    const float z  = fmaf(accl[m][e], INV, acc[m][e]);
                    const float ex = __builtin_amdgcn_exp2f(z);   // z pre-scaled
                    const float r  = __builtin_amdgcn_rcpf(ex + 1.0f);
                    hf[m][e] = fmaf(-2.0f, r, 1.0f);              // tanh
                }
                const auto hiA = __builtin_amdgcn_cvt_pkrtz(hf[m][0], hf[m][1]);
                const auto hiB = __builtin_amdgcn_cvt_pkrtz(hf[m][2], hf[m][3]);
                bhi[m] = as_h4(__builtin_shufflevector(hiA, hiB, 0, 1, 2, 3));
                const auto loA = __builtin_amdgcn_cvt_pkrtz(
                    (hf[m][0] - (float)hiA[0]) * 1024.0f,
                    (hf[m][1] - (float)hiA[1]) * 1024.0f);
                const auto loB = __builtin_amdgcn_cvt_pkrtz(
                    (hf[m][2] - (float)hiB[0]) * 1024.0f,
                    (hf[m][3] - (float)hiB[1]) * 1024.0f);
                blo[m] = as_h4(__builtin_shufflevector(loA, loB, 0, 1, 2, 3));
            }
        }
        xq = xqn;
    }

    // out[b=bb+c] = sum_j h[j]*W_fc[j] + b_fc. Lane covers j = m*16+4g+e;
    // xor-16 + xor-32 sums the 4 g-groups per batch column c.
    float pr = 0.0f;
#pragma unroll
    for (int m = 0; m < 4; ++m)
#pragma unroll
        for (int e = 0; e < 4; ++e) pr = fmaf(hf[m][e], wfc_f[m][e], pr);
    pr += __shfl_xor(pr, 16);
    pr += __shfl_xor(pr, 32);
    if (l < NB) out[bb + l] = pr + bfc;
}

extern "C" void kernel_launch(void* const* d_in, const int* in_sizes, int n_in,
                              void* d_out, int out_size, void* d_ws, size_t ws_size,
                              hipStream_t stream) {
    (void)d_ws; (void)ws_size; (void)n_in; (void)out_size;
    const float* x    = (const float*)d_in[0];
    const float* W_ih = (const float*)d_in[1];
    const float* W_hh = (const float*)d_in[2];
    const float* b_ih = (const float*)d_in[3];
    const float* b_hh = (const float*)d_in[4];
    const float* W_fc = (const float*)d_in[5];
    const float* b_fc = (const float*)d_in[6];
    float* out = (float*)d_out;

    const int B = in_sizes[0] / TSTEPS;       // 2048
    rnn_mfma<<<dim3(B / NB), dim3(64), 0, stream>>>(x, W_ih, W_hh, b_ih, b_hh,
                                                    W_fc, b_fc, out);
}

// Round 15
// 153.942 us; speedup vs baseline: 2.2937x; 2.2937x over previous
//
#include <hip/hip_runtime.h>

#define HID 50
#define TSTEPS 512

typedef float f32x4 __attribute__((ext_vector_type(4)));

// 2 batches per wave, 2 rows per lane, pure fp32.
//   lanes 0-31  = batch A (bh=0), lanes 32-63 = batch B (bh=1)
//   lane (bh,r) owns rows j0=2r, j1=2r+1 of its batch (r=25..31 padded zero)
// The h broadcast is 13 ds_read_b128 per step SHARED by both batches: each
// instr touches two 16B segments (one per half-wave) -- 2-way aliasing is
// free (m136), so DS return traffic per batch HALVES vs round 4 (the real
// bottleneck there: 8 waves/CU x 14 bcast reads x ~4cyc ~ 70% DS-pipe load).
// Wave count halves to 1024 = exactly 1 wave on every SIMD: whole chip busy,
// no same-phase co-resident convoy. Scalar FMAs (pk half-rate, r5; readlane
// SGPR-hazard-bound, r10; MFMA 1/8-machine latency-bound, r12).
__global__ __launch_bounds__(64) __attribute__((amdgpu_waves_per_eu(1, 1)))
void rnn_fused(
    const float* __restrict__ x,      // [B, 512, 1]
    const float* __restrict__ W_ih,   // [50, 1]
    const float* __restrict__ W_hh,   // [50, 50]
    const float* __restrict__ b_ih,   // [50]
    const float* __restrict__ b_hh,   // [50]
    const float* __restrict__ W_fc,   // [1, 50]
    const float* __restrict__ b_fc,   // [1]
    float* __restrict__ out)          // [B, 1]
{
    const int l  = threadIdx.x;
    const int bh = l >> 5;            // which batch of the pair
    const int r  = l & 31;            // row-pair index
    const int b  = blockIdx.x * 2 + bh;
    const int j0 = 2 * r, j1 = 2 * r + 1;
    const bool v0 = (j0 < HID), v1 = (j1 < HID);
    const int jj0 = v0 ? j0 : 0, jj1 = v1 ? j1 : 0;
    const float SC = 2.8853900817779268f;   // 2*log2(e)

    __shared__ __align__(16) float ht[2][64];   // h tables; slots 50..63 = 0
    __shared__ float xs[2][32];                 // x chunk, 32 steps per batch

    // Row weights (pre-scaled by SC); padded rows fully zeroed. w[50..51]=0
    // kills the garbage in quad 12's tail slots.
    float w0[52], w1[52];
#pragma unroll
    for (int k = 0; k < HID; ++k) {
        w0[k] = v0 ? W_hh[jj0 * HID + k] * SC : 0.0f;
        w1[k] = v1 ? W_hh[jj1 * HID + k] * SC : 0.0f;
    }
    w0[50] = w0[51] = 0.0f;
    w1[50] = w1[51] = 0.0f;

    const float wih0  = v0 ? W_ih[jj0] * SC : 0.0f;
    const float wih1  = v1 ? W_ih[jj1] * SC : 0.0f;
    const float btot0 = v0 ? (b_ih[jj0] + b_hh[jj0]) * SC : 0.0f;
    const float btot1 = v1 ? (b_ih[jj1] + b_hh[jj1]) * SC : 0.0f;
    const float wfc0  = v0 ? W_fc[jj0] : 0.0f;
    const float wfc1  = v1 ? W_fc[jj1] : 0.0f;
    const float bfc   = b_fc[0];

    const float* xb = x + (size_t)b * TSTEPS;
    float xv = xb[r];                 // 32 steps per chunk, lane r holds step r
    float hn0 = 0.0f, hn1 = 0.0f;

    for (int c = 0; c < TSTEPS / 32; ++c) {
        xs[bh][r] = xv;               // stage chunk (same-wave in-order DS)
        float xvn = 0.0f;
        if (c + 1 < TSTEPS / 32) xvn = xb[(c + 1) * 32 + r];

        for (int g = 0; g < 4; ++g) {
#pragma unroll
            for (int ii = 0; ii < 8; ++ii) {
                const int t = g * 8 + ii;

                // publish h pair (rows 2r,2r+1 -> slots 2r,2r+1): ds_write_b64
                float2 hp; hp.x = hn0; hp.y = hn1;
                *reinterpret_cast<float2*>(&ht[bh][j0]) = hp;

                const float xt = xs[bh][t];           // 2-segment bcast b32
                float a0 = fmaf(xt, wih0, btot0), a1 = 0.0f, a2 = 0.0f, a3 = 0.0f;
                float c0 = fmaf(xt, wih1, btot1), c1 = 0.0f, c2 = 0.0f, c3 = 0.0f;

                const f32x4* h4 = reinterpret_cast<const f32x4*>(&ht[bh][0]);
#pragma unroll
                for (int q = 0; q < 13; ++q) {
                    const f32x4 p = h4[q];            // 2-segment bcast b128
                    a0 = fmaf(p.x, w0[4 * q + 0], a0);
                    a1 = fmaf(p.y, w0[4 * q + 1], a1);
                    a2 = fmaf(p.z, w0[4 * q + 2], a2);
                    a3 = fmaf(p.w, w0[4 * q + 3], a3);
                    c0 = fmaf(p.x, w1[4 * q + 0], c0);
                    c1 = fmaf(p.y, w1[4 * q + 1], c1);
                    c2 = fmaf(p.z, w1[4 * q + 2], c2);
                    c3 = fmaf(p.w, w1[4 * q + 3], c3);
                }
                const float z0 = (a0 + a1) + (a2 + a3);   // scaled by 2*log2e
                const float z1 = (c0 + c1) + (c2 + c3);

                // tanh(s) = 1 - 2/(exp2(z)+1); saturates correctly at +-inf
                const float e0 = __builtin_amdgcn_exp2f(z0);
                const float e1 = __builtin_amdgcn_exp2f(z1);
                hn0 = fmaf(-2.0f, __builtin_amdgcn_rcpf(e0 + 1.0f), 1.0f);
                hn1 = fmaf(-2.0f, __builtin_amdgcn_rcpf(e1 + 1.0f), 1.0f);
            }
        }
        xv = xvn;
    }

    // out[b] = sum_j h[j]*W_fc[j] + b_fc; reduce within each 32-lane half.
    float pr = fmaf(hn1, wfc1, hn0 * wfc0);
#pragma unroll
    for (int off = 16; off >= 1; off >>= 1) pr += __shfl_xor(pr, off);
    if (r == 0) out[b] = pr + bfc;
}

extern "C" void kernel_launch(void* const* d_in, const int* in_sizes, int n_in,
                              void* d_out, int out_size, void* d_ws, size_t ws_size,
                              hipStream_t stream) {
    (void)d_ws; (void)ws_size; (void)n_in; (void)out_size;
    const float* x    = (const float*)d_in[0];
    const float* W_ih = (const float*)d_in[1];
    const float* W_hh = (const float*)d_in[2];
    const float* b_ih = (const float*)d_in[3];
    const float* b_hh = (const float*)d_in[4];
    const float* W_fc = (const float*)d_in[5];
    const float* b_fc = (const float*)d_in[6];
    float* out = (float*)d_out;

    const int B = in_sizes[0] / TSTEPS;   // 2048
    rnn_fused<<<dim3(B / 2), dim3(64), 0, stream>>>(x, W_ih, W_hh, b_ih, b_hh,
                                                    W_fc, b_fc, out);
}

// Round 16
// 102.385 us; speedup vs baseline: 3.4487x; 1.5036x over previous
//
#include <hip/hip_runtime.h>

#define HID 50
#define TSTEPS 512

typedef _Float16 h2v __attribute__((ext_vector_type(2)));

// v_dot2_f32_f16: d = a.x*b.x + a.y*b.y + c, fp32 accumulate. Full-rate on
// CDNA (the 2x-fp16 path; unlike v_pk_fma_f32 which measured half-rate, r5).
__device__ __forceinline__ float fdot2(h2v a, h2v b, float c) {
#if __has_builtin(__builtin_amdgcn_fdot2)
    return __builtin_amdgcn_fdot2(a, b, c, false);
#else
    asm("v_dot2_f32_f16 %0, %1, %2, %0" : "+v"(c) : "v"(a), "v"(b));
    return c;
#endif
}

__device__ __forceinline__ h2v bits_to_h2(unsigned u) {
    h2v r; __builtin_memcpy(&r, &u, sizeof(r)); return r;
}

// R4 skeleton (best measured: 139us; 1 batch/wave, 2 waves/SIMD, barrier
// version) with the MAC count halved via fp16 dot2:
//  - lane j publishes h[j] as fp16 (RTN) -> 128B LDS table
//  - broadcast = 7 ds_read_b128 (56 halves; slots 50+ inert via zero weights)
//  - dot = 25 v_dot2_f32_f16 (fp32 acc), vs 52 scalar FMAs in R4
//  - x-projection, biases, tanh all remain exact fp32
// Cross-round facts driving this: issue-count x occupancy is the binding
// constraint (R4 325 cyc/step-slot @2 waves/SIMD beats all 1-wave/SIMD
// variants); DS congestion secondary (R15); pk half-rate (R5); readlane
// SGPR-hazard-bound (R10); MFMA occupancy-starved (R12).
__global__ __launch_bounds__(64) __attribute__((amdgpu_waves_per_eu(2, 2)))
void rnn_fused(
    const float* __restrict__ x,      // [B, 512, 1]
    const float* __restrict__ W_ih,   // [50, 1]
    const float* __restrict__ W_hh,   // [50, 50]
    const float* __restrict__ b_ih,   // [50]
    const float* __restrict__ b_hh,   // [50]
    const float* __restrict__ W_fc,   // [1, 50]
    const float* __restrict__ b_fc,   // [1]
    float* __restrict__ out)          // [B, 1]
{
    const int b = blockIdx.x;
    const int j = threadIdx.x;        // 0..63; lanes 50..63 duplicate row 0
    __shared__ __align__(16) _Float16 hht[64];   // h table, fp16
    __shared__ float xbuf[64];

    const int jj = (j < HID) ? j : 0;
    const float SC = 2.8853900817779268f;   // 2*log2(e)

    // Weight pairs (W*SC as fp16): w2[m] covers h[2m],h[2m+1], m=0..24.
    h2v w2[25];
#pragma unroll
    for (int m = 0; m < 25; ++m) {
        h2v t;
        t.x = (_Float16)(W_hh[jj * HID + 2 * m]     * SC);
        t.y = (_Float16)(W_hh[jj * HID + 2 * m + 1] * SC);
        w2[m] = t;
    }

    const float wih  = W_ih[jj] * SC;
    const float btot = (b_ih[jj] + b_hh[jj]) * SC;
    const float wfc  = (j < HID) ? W_fc[jj] : 0.0f;
    const float bfc  = b_fc[0];

    const float* xb = x + (size_t)b * TSTEPS;
    float xv = xb[j];                 // 64 timesteps of x, one per lane
    float hn = 0.0f;
    hht[j] = (_Float16)0.0f;          // h0 = 0
    __syncthreads();

    for (int c = 0; c < TSTEPS / 64; ++c) {
        xbuf[j] = xv;
        float xv_next = 0.0f;
        if (c + 1 < TSTEPS / 64) xv_next = xb[(c + 1) * 64 + j];
        __syncthreads();

        for (int g = 0; g < 8; ++g) {
#pragma unroll
            for (int ii = 0; ii < 8; ++ii) {
                const int t = g * 8 + ii;
                const float xt = xbuf[t];               // uniform addr bcast
                float a0 = fmaf(xt, wih, btot);         // fp32 x-part + bias
                float a1 = 0.0f, a2 = 0.0f, a3 = 0.0f;

                // broadcast h as 7x b128 (28 pairs; use pairs 0..24)
                const uint4* h8 = reinterpret_cast<const uint4*>(hht);
#pragma unroll
                for (int q = 0; q < 7; ++q) {
                    const uint4 u = h8[q];              // ds_read_b128 bcast
                    const int m = 4 * q;
                    a0 = fdot2(bits_to_h2(u.x), w2[m], a0);
                    if (m + 1 < 25) a1 = fdot2(bits_to_h2(u.y), w2[m + 1], a1);
                    if (m + 2 < 25) a2 = fdot2(bits_to_h2(u.z), w2[m + 2], a2);
                    if (m + 3 < 25) a3 = fdot2(bits_to_h2(u.w), w2[m + 3], a3);
                }
                const float z = (a0 + a1) + (a2 + a3);  // scaled by 2*log2e

                // tanh(s) = 1 - 2/(exp2(z)+1); saturates correctly at +-inf
                const float e = __builtin_amdgcn_exp2f(z);
                const float r = __builtin_amdgcn_rcpf(e + 1.0f);
                hn = fmaf(-2.0f, r, 1.0f);

                hht[j] = (_Float16)hn;                  // publish fp16 (RTN)
                __syncthreads();
            }
        }
        xv = xv_next;
    }

    // out[b] = sum_j h[j] * W_fc[j] + b_fc  (lanes >= 50 contribute 0);
    // hn kept fp32 for the epilogue.
    float pr = hn * wfc;
#pragma unroll
    for (int off = 32; off >= 1; off >>= 1) pr += __shfl_xor(pr, off);
    if (j == 0) out[b] = pr + bfc;
}

extern "C" void kernel_launch(void* const* d_in, const int* in_sizes, int n_in,
                              void* d_out, int out_size, void* d_ws, size_t ws_size,
                              hipStream_t stream) {
    (void)d_ws; (void)ws_size; (void)n_in; (void)out_size;
    const float* x    = (const float*)d_in[0];
    const float* W_ih = (const float*)d_in[1];
    const float* W_hh = (const float*)d_in[2];
    const float* b_ih = (const float*)d_in[3];
    const float* b_hh = (const float*)d_in[4];
    const float* W_fc = (const float*)d_in[5];
    const float* b_fc = (const float*)d_in[6];
    float* out = (float*)d_out;

    const int B = in_sizes[0] / TSTEPS;   // 2048
    rnn_fused<<<dim3(B), dim3(64), 0, stream>>>(x, W_ih, W_hh, b_ih, b_hh, W_fc, b_fc, out);
}